// Round 8
// baseline (332.958 us; speedup 1.0000x reference)
//
#include <hip/hip_runtime.h>
#include <cstdint>

typedef unsigned short u16;
typedef unsigned int u32;
typedef __attribute__((ext_vector_type(8))) short short8;   // 8 x bf16 bits
typedef __attribute__((ext_vector_type(4))) float f32x4;
typedef __attribute__((ext_vector_type(4))) unsigned short u16x4;

#define S_ 4096
#define SD 2048

__device__ __forceinline__ u16 f2bf(float f) {
  union { float f; u32 u; } v; v.f = f;
  u32 r = v.u + 0x7fffu + ((v.u >> 16) & 1u);
  return (u16)(r >> 16);
}
#if __has_builtin(__builtin_amdgcn_cvt_pk_bf16_f32)
__device__ __forceinline__ u32 pkbf(float a, float b) {
  auto r = __builtin_amdgcn_cvt_pk_bf16_f32(a, b);
  u32 o; __builtin_memcpy(&o, &r, 4); return o;
}
#else
__device__ __forceinline__ u32 pkbf(float a, float b) {
  union { float f; u32 u; } ua, ub; ua.f = a; ub.f = b;
  return __builtin_amdgcn_perm(ub.u + 0x8000u, ua.u + 0x8000u, 0x07060302u);
}
#endif
__device__ __forceinline__ f32x4 mfma16(short8 a, short8 b, f32x4 c) {
  return __builtin_amdgcn_mfma_f32_16x16x32_bf16(a, b, c, 0, 0, 0);
}
__device__ __forceinline__ void async16(const void* g, void* l) {
  __builtin_amdgcn_global_load_lds((__attribute__((address_space(1))) void*)g,
                                   (__attribute__((address_space(3))) void*)l,
                                   16, 0, 0);
}

// chunk tables for attn12: 40 z-slots per (b,h), <=8 tiles each, longest first.
// qt 15..12: 4 chunks; 11..8: 3; 7..4: 2; 3..0: 1 (z>=36 -> direct write).
__device__ const signed char ZQT[40] = {15,15,15,15, 14,14,14,14, 13,13,13,13, 12,12,12,12,
                                        11,11,11, 10,10,10, 9,9,9, 8,8,8,
                                        7,7, 6,6, 5,5, 4,4, 3,2,1,0};
__device__ const signed char ZC0[40] = {0,8,16,24, 0,8,16,23, 0,7,14,21, 0,7,14,20,
                                        0,8,16, 0,8,15, 0,7,14, 0,6,12,
                                        0,8, 0,7, 0,6, 0,5, 0,0,0,0};
__device__ const signed char ZC1[40] = {7,15,23,31, 7,15,22,29, 6,13,20,27, 6,13,19,25,
                                        7,15,23, 7,14,21, 6,13,19, 5,11,17,
                                        7,15, 6,13, 5,11, 4,9, 7,5,3,1};

// ---------------- fused cast kernel ----------------
__global__ __launch_bounds__(256) void cast_all(const float* __restrict__ hs,
                                                const float* __restrict__ Wq,
                                                const float* __restrict__ Wk,
                                                const float* __restrict__ Wv,
                                                const float* __restrict__ Wo,
                                                u16* __restrict__ dstW,
                                                u16* __restrict__ dstX) {
  int bid = blockIdx.x;
  if (bid < 4096) {
    int gid = bid * 256 + threadIdx.x;
    int wsel = gid >> 18;
    int off  = (gid & 262143) * 4;
    const float* src = (wsel == 0) ? Wq : (wsel == 1) ? Wk : (wsel == 2) ? Wv : Wo;
    float scl = (wsel == 0) ? 0.18033688f : 1.0f;   // 1/sqrt(64)*log2(e) folded into Wq
    f32x4 v = *(const f32x4*)(src + off);
    u16x4 o; o.x = f2bf(v.x * scl); o.y = f2bf(v.y * scl);
    o.z = f2bf(v.z * scl); o.w = f2bf(v.w * scl);
    *(u16x4*)(dstW + (size_t)wsel * 1048576 + off) = o;
  } else {
    int gid = (bid - 4096) * 256 + threadIdx.x;
    int e = gid * 4;
    int m = e >> 10, col = e & 1023;
    int b = m >> 11, sm = m & 2047;
    const float* src = hs + ((size_t)(b * S_ + 2 * sm) << 10) + col;
    f32x4 v = *(const f32x4*)src;
    u16x4 o; o.x = f2bf(v.x); o.y = f2bf(v.y); o.z = f2bf(v.z); o.w = f2bf(v.w);
    *(u16x4*)(dstX + ((size_t)m << 10) + col) = o;
  }
}

// ---------------- 128x128 double-buffered GEMM body (K=1024, B^T), templated epilogue ----------------
// MODE 0: C row-major [.][1024], col n (<1024)                      (Q output)
// MODE 1: K fragment-layout Kp[b][h][kb][key-frag]  (tok=m0+r, d=n-1024, no kappa)
// MODE 2: V fragment-layout Vp[b][h][kb][d-frag]    (m=h*64+d, tok=n, kappa-permuted k)
template<int MODE>
__device__ __forceinline__ void gemm_body128_t(const u16* __restrict__ A,
                                               const u16* __restrict__ B,
                                               u16* __restrict__ C,
                                               int bm, int bn, char* lA, char* lB) {
  const int tid = threadIdx.x, lane = tid & 63, w = tid >> 6;
  const int quad = lane >> 4, l15 = lane & 15;
  const int wm = (w & 1) * 64, wn = (w >> 1) * 64;
  f32x4 acc[4][4] = {};

  auto stage = [&](int buf, int k0) {
#pragma unroll
    for (int i = 0; i < 2; i++) {
      int p = i * 256 + tid;
      int row = p >> 2, cp = p & 3;
      int c = cp ^ ((row ^ (row >> 2)) & 3);
      async16(A + (size_t)(bm + row) * 1024 + k0 + c * 8,
              lA + buf * 8192 + i * 4096 + w * 1024);
      async16(B + (size_t)(bn + row) * 1024 + k0 + c * 8,
              lB + buf * 8192 + i * 4096 + w * 1024);
    }
  };

  stage(0, 0);
#pragma unroll 1
  for (int kt = 0; kt < 32; kt++) {
    __syncthreads();
    if (kt + 1 < 32) stage((kt + 1) & 1, (kt + 1) * 32);
    const char* A_ = lA + (kt & 1) * 8192;
    const char* B_ = lB + (kt & 1) * 8192;
    short8 af[4], bf[4];
#pragma unroll
    for (int mi = 0; mi < 4; mi++) {
      int row = wm + mi * 16 + l15;
      af[mi] = *(const short8*)(A_ + (row * 4 + (quad ^ ((row ^ (row >> 2)) & 3))) * 16);
    }
#pragma unroll
    for (int ni = 0; ni < 4; ni++) {
      int row = wn + ni * 16 + l15;
      bf[ni] = *(const short8*)(B_ + (row * 4 + (quad ^ ((row ^ (row >> 2)) & 3))) * 16);
    }
#pragma unroll
    for (int mi = 0; mi < 4; mi++)
#pragma unroll
      for (int ni = 0; ni < 4; ni++)
        acc[mi][ni] = mfma16(af[mi], bf[ni], acc[mi][ni]);
  }

#pragma unroll
  for (int mi = 0; mi < 4; mi++)
#pragma unroll
    for (int ni = 0; ni < 4; ni++) {
      int m0 = bm + wm + mi * 16 + quad * 4;
      int n = bn + wn + ni * 16 + l15;
      size_t base;
      if (MODE == 0) {
        base = (size_t)m0 * 1024 + n;               // stride 1024 per r
      } else if (MODE == 1) {
        // tok = m0 + r (b, kb, key constant across r since m0 % 4 == 0)
        int bb = m0 >> 11, t = m0 & 2047, kb = t >> 6, key0 = t & 63;
        int d = n - 1024;
        int hh = d >> 6, dd = d & 63, ch = dd >> 3, e = dd & 7;
        base = ((size_t)(((bb * 16 + hh) * 32 + kb)) << 12)
             + (key0 >> 4) * 1024 + (ch >> 2) * 512 + (ch & 3) * 128
             + (key0 & 15) * 8 + e;                  // stride 8 per r
      } else {
        // m = m0 + r = h*64 + d (h, d>>4 constant across r); tok = n
        int hh = m0 >> 6, d0 = m0 & 63;
        int bb = n >> 11, t = n & 2047, kb = t >> 6, kk = t & 63;
        int kh = (kk & 32) | (((kk >> 2) & 3) << 3) | (((kk >> 4) & 1) << 2) | (kk & 3);
        int ch = kh >> 3, e = kh & 7;
        base = ((size_t)(((bb * 16 + hh) * 32 + kb)) << 12)
             + (d0 >> 4) * 1024 + (ch >> 2) * 512 + (ch & 3) * 128
             + (d0 & 15) * 8 + e;                    // stride 8 per r
      }
#pragma unroll
      for (int r = 0; r < 4; r++) {
        size_t off = (MODE == 0) ? base + (size_t)r * 1024 : base + (size_t)r * 8;
        C[off] = f2bf(acc[mi][ni][r]);
      }
    }
}

// fused QKV projection: blocks 0..511 -> Q / Kp from X @ [Wq;Wk]^T (M=4096,N=2048)
//                       blocks 512..767 -> Vp from Wv @ X^T       (M=1024,N=4096)
__global__ __launch_bounds__(256) void qkv_gemm(const u16* __restrict__ X,
                                                const u16* __restrict__ Wbf,
                                                u16* __restrict__ Qb,
                                                u16* __restrict__ Kp,
                                                u16* __restrict__ Vp) {
  __shared__ __align__(16) char lA[16384];
  __shared__ __align__(16) char lB[16384];
  int bid = blockIdx.x;
  if (bid < 512) {
    int bm = (bid >> 4) * 128, bn = (bid & 15) * 128;
    if (bn < 1024) gemm_body128_t<0>(X, Wbf, Qb, bm, bn, lA, lB);
    else           gemm_body128_t<1>(X, Wbf, Kp, bm, bn, lA, lB);
  } else {
    int b2 = bid - 512;
    gemm_body128_t<2>(Wbf + 2 * 1048576, X, Vp, (b2 >> 5) * 128, (b2 & 31) * 128, lA, lB);
  }
}

// ---------------- O-projection: BM=64 x BN=128, wave 32x64 (512 blocks, 24KB) ----------------
__global__ __launch_bounds__(256) void oproj(const u16* __restrict__ A,
                                             const u16* __restrict__ B,
                                             const float* __restrict__ bo,
                                             float* __restrict__ out) {
  __shared__ __align__(16) char lA[8192];    // 2 x 4KB
  __shared__ __align__(16) char lB[16384];   // 2 x 8KB
  const int tid = threadIdx.x, lane = tid & 63, w = tid >> 6;
  const int quad = lane >> 4, l15 = lane & 15;
  const int bm = blockIdx.y * 64, bn = blockIdx.x * 128;
  const int wm = (w & 1) * 32, wn = (w >> 1) * 64;
  f32x4 acc[2][4] = {};

  auto stage = [&](int buf, int k0) {
    {
      int row = tid >> 2, cp = tid & 3;
      int c = cp ^ ((row ^ (row >> 2)) & 3);
      async16(A + (size_t)(bm + row) * 1024 + k0 + c * 8, lA + buf * 4096 + w * 1024);
    }
#pragma unroll
    for (int i = 0; i < 2; i++) {
      int p = i * 256 + tid;
      int row = p >> 2, cp = p & 3;
      int c = cp ^ ((row ^ (row >> 2)) & 3);
      async16(B + (size_t)(bn + row) * 1024 + k0 + c * 8, lB + buf * 8192 + i * 4096 + w * 1024);
    }
  };

  stage(0, 0);
#pragma unroll 1
  for (int kt = 0; kt < 32; kt++) {
    __syncthreads();
    if (kt + 1 < 32) stage((kt + 1) & 1, (kt + 1) * 32);
    const char* A_ = lA + (kt & 1) * 4096;
    const char* B_ = lB + (kt & 1) * 8192;
    short8 af[2], bf[4];
#pragma unroll
    for (int mi = 0; mi < 2; mi++) {
      int row = wm + mi * 16 + l15;
      af[mi] = *(const short8*)(A_ + (row * 4 + (quad ^ ((row ^ (row >> 2)) & 3))) * 16);
    }
#pragma unroll
    for (int ni = 0; ni < 4; ni++) {
      int row = wn + ni * 16 + l15;
      bf[ni] = *(const short8*)(B_ + (row * 4 + (quad ^ ((row ^ (row >> 2)) & 3))) * 16);
    }
#pragma unroll
    for (int mi = 0; mi < 2; mi++)
#pragma unroll
      for (int ni = 0; ni < 4; ni++)
        acc[mi][ni] = mfma16(af[mi], bf[ni], acc[mi][ni]);
  }
#pragma unroll
  for (int mi = 0; mi < 2; mi++)
#pragma unroll
    for (int ni = 0; ni < 4; ni++) {
      int n = bn + wn + ni * 16 + l15;
      float bias = bo[n];
#pragma unroll
      for (int r = 0; r < 4; r++) {
        int m = bm + wm + mi * 16 + quad * 4 + r;   // m = b*2048 + sm
        int bb = m >> 11, sm = m & 2047;
        size_t grow = ((size_t)(bb * S_ + 2 * sm)) << 10;
        out[grow + n] = acc[mi][ni][r] + bias;
        out[grow + 1024 + n] = bias;                // odd row = bo only
      }
    }
}

// ---------------- flash attention v12: attn11 inner loop + fine k-split + f32 atomic combine ----
// attn11 showed residency is GRID-limited (12 waves/CU supplied, 24 permitted at VGPR=80, LDS=0).
// Split k into <=8-tile chunks (40 z-slots, 1280 blocks = 20 waves/CU). exp2-softmax partials
// combine by pure addition -> accumulate O,l partials via f32 atomicAdd into a zeroed buffer
// (more accurate than the old bf16 Op1 path). Rows qt<=3 (single chunk) write direct.
__global__ __launch_bounds__(256, 4) void attn12(const u16* __restrict__ Qb,
                                                 const u16* __restrict__ Kp,
                                                 const u16* __restrict__ Vp,
                                                 u16* __restrict__ O,
                                                 float* __restrict__ Opart,
                                                 float* __restrict__ lpart) {
  const int tid = threadIdx.x, lane = tid & 63, w = tid >> 6;
  const int quad = lane >> 4, l15 = lane & 15;
  const int h = blockIdx.x, b = blockIdx.y;
  const int z = (int)blockIdx.z;
  const int qt = ZQT[z], c0 = ZC0[z], c1 = ZC1[z];
  const bool par = (z < 36);         // qt>=4 -> atomic partial path
  const int qb = qt * 128 + w * 32;
  const int qt2 = 2 * qt;            // first diagonal k-tile

  short8 qf[2][2];
#pragma unroll
  for (int n = 0; n < 2; n++) {
    const u16* qp = Qb + (size_t)(b * SD + qb + n * 16 + l15) * 1024 + h * 64 + quad * 8;
    qf[n][0] = *(const short8*)qp;
    qf[n][1] = *(const short8*)(qp + 32);
  }

  const size_t bh = (size_t)(b * 16 + h) * 32;
  f32x4 oacc[2][4] = {};
  f32x4 l4v[2] = {};
  const f32x4 zf = {};

#pragma unroll 1
  for (int kt = c0; kt <= c1; kt++) {
    const u16* K_ = Kp + ((bh + kt) << 12);
    const u16* V_ = Vp + ((bh + kt) << 12);
    const bool diag = (kt >= qt2);   // wave-uniform

    // batch all K fragment loads (coalesced 64x16B each)
    short8 kf[4][2];
#pragma unroll
    for (int m = 0; m < 4; m++) {
      kf[m][0] = *(const short8*)(K_ + m * 1024 + lane * 8);
      kf[m][1] = *(const short8*)(K_ + m * 1024 + 512 + lane * 8);
    }
    // QK MFMAs
    f32x4 s[4][2];
#pragma unroll
    for (int m = 0; m < 4; m++)
#pragma unroll
      for (int n = 0; n < 2; n++) {
        f32x4 a = mfma16(kf[m][0], qf[n][0], zf);
        s[m][n] = mfma16(kf[m][1], qf[n][1], a);
      }
    // V fragment loads issued now: latency hides under mask/exp/pack VALU below
    short8 vf[4][2];
#pragma unroll
    for (int m = 0; m < 4; m++) {
      vf[m][0] = *(const short8*)(V_ + m * 1024 + lane * 8);
      vf[m][1] = *(const short8*)(V_ + m * 1024 + 512 + lane * 8);
    }
    u32 pw[2][8];
#pragma unroll
    for (int m = 0; m < 4; m++)
#pragma unroll
      for (int n = 0; n < 2; n++) {
        f32x4 a = s[m][n];
        if (diag) {
          int qrel = w * 32 + n * 16 + l15;
          int kd = (kt - qt2) * 64 + m * 16 + quad * 4;
#pragma unroll
          for (int r = 0; r < 4; r++)
            if (kd + r > qrel) a[r] = -1e30f;
        }
        f32x4 p;
#pragma unroll
        for (int r = 0; r < 4; r++) p[r] = exp2f(a[r]);
        l4v[n] += p;
        pw[n][m * 2]     = pkbf(p[0], p[1]);
        pw[n][m * 2 + 1] = pkbf(p[2], p[3]);
      }
    short8 pf[2][2];
#pragma unroll
    for (int n = 0; n < 2; n++) {
      __builtin_memcpy(&pf[n][0], &pw[n][0], 16);
      __builtin_memcpy(&pf[n][1], &pw[n][4], 16);
    }
    // PV MFMAs
#pragma unroll
    for (int m = 0; m < 4; m++)
#pragma unroll
      for (int n = 0; n < 2; n++) {
        oacc[n][m] = mfma16(vf[m][0], pf[n][0], oacc[n][m]);
        oacc[n][m] = mfma16(vf[m][1], pf[n][1], oacc[n][m]);
      }
  }

#pragma unroll
  for (int n = 0; n < 2; n++) {
    float l = (l4v[n][0] + l4v[n][1]) + (l4v[n][2] + l4v[n][3]);
    l += __shfl_xor(l, 16, 64);
    l += __shfl_xor(l, 32, 64);
    if (!par) {
      float inv = 1.0f / l;
      u16* op = O + (size_t)(b * SD + qb + n * 16 + l15) * 1024 + h * 64;
#pragma unroll
      for (int m = 0; m < 4; m++) {
        u16x4 ov;
#pragma unroll
        for (int r = 0; r < 4; r++) ov[r] = f2bf(oacc[n][m][r] * inv);
        *(u16x4*)(op + m * 16 + quad * 4) = ov;
      }
    } else {
      // qt>=4 -> qb>=512; row index within [0, 3072)
      int rr = b * 1536 + (qb + n * 16 + l15 - 512);
      float* p0 = Opart + ((size_t)rr << 10) + h * 64 + quad * 4;
#pragma unroll
      for (int m = 0; m < 4; m++)
#pragma unroll
        for (int r = 0; r < 4; r++)
          atomicAdd(p0 + m * 16 + r, oacc[n][m][r]);
      if (quad == 0) atomicAdd(&lpart[rr * 16 + h], l);
    }
  }
}

// ---------------- normalize atomic partials for rows q in [512,2048): O = Opart / l ----------------
__global__ __launch_bounds__(256) void norm_po(const float* __restrict__ Opart,
                                               const float* __restrict__ lpart,
                                               u16* __restrict__ O) {
  int gid = blockIdx.x * 256 + threadIdx.x;    // 786432 threads x 4 elems
  int e = gid * 4;
  int row = e >> 10, d0 = e & 1023;            // row in [0, 3072)
  float l = lpart[row * 16 + (d0 >> 6)];
  float inv = 1.0f / l;
  f32x4 a = *(const f32x4*)(Opart + ((size_t)row << 10) + d0);
  int bb = row >= 1536 ? 1 : 0;
  int rr = row - bb * 1536;
  u16* op = O + ((size_t)(bb * SD + 512 + rr) << 10) + d0;
  u16x4 o;
#pragma unroll
  for (int r = 0; r < 4; r++) o[r] = f2bf(a[r] * inv);
  *(u16x4*)op = o;
}

// ---------------- host ----------------
extern "C" void kernel_launch(void* const* d_in, const int* in_sizes, int n_in,
                              void* d_out, int out_size, void* d_ws, size_t ws_size,
                              hipStream_t stream) {
  (void)in_sizes; (void)n_in; (void)out_size; (void)ws_size;
  const float* hs = (const float*)d_in[0];
  const float* Wq = (const float*)d_in[1];
  const float* Wk = (const float*)d_in[2];
  const float* Wv = (const float*)d_in[3];
  const float* Wo = (const float*)d_in[4];
  const float* bo = (const float*)d_in[5];
  float* out = (float*)d_out;
  char* ws = (char*)d_ws;

  u16* Xbf = (u16*)ws;                            // [4096][1024] even-row hs, bf16 (dead after qkv_gemm)
  u16* Wbf = (u16*)(ws + (8u << 20));             // 4 x [1024][1024] bf16 (q,k,v,o); q,k,v dead after qkv_gemm
  u16* Qb  = (u16*)(ws + (16u << 20));            // [4096][1024]  Q (pre-scaled, log2 domain)
  u16* Kp  = (u16*)(ws + (24u << 20));            // [2][16][32][4096] K fragment-order
  u16* Vp  = (u16*)(ws + (32u << 20));            // [2][16][32][4096] V fragment-order (kappa)
  u16* Ob  = (u16*)(ws + (40u << 20));            // [4096][1024]  attn out

  float* Opart = (float*)ws;                      // f32 partials [3072][1024] = 12MB (dead Xbf/Wq/Wk)
  float* lpart = (float*)(ws + (12u << 20));      // f32 l partials [3072][16] = 192KB (dead Wv)

  cast_all<<<8192, 256, 0, stream>>>(hs, Wq, Wk, Wv, Wo, Wbf, Xbf);
  qkv_gemm<<<768, 256, 0, stream>>>(Xbf, Wbf, Qb, Kp, Vp);
  hipMemsetAsync(ws, 0, (12u << 20) + (1u << 18), stream);
  attn12<<<dim3(16, 2, 40), 256, 0, stream>>>(Qb, Kp, Vp, Ob, Opart, lpart);
  norm_po<<<3072, 256, 0, stream>>>(Opart, lpart, Ob);
  oproj<<<dim3(8, 64), 256, 0, stream>>>(Ob, Wbf + 3 * 1048576, bo, out);
}

// Round 10
// 298.348 us; speedup vs baseline: 1.1160x; 1.1160x over previous
//
#include <hip/hip_runtime.h>
#include <cstdint>

typedef unsigned short u16;
typedef unsigned int u32;
typedef __attribute__((ext_vector_type(8))) short short8;   // 8 x bf16 bits
typedef __attribute__((ext_vector_type(4))) float f32x4;
typedef __attribute__((ext_vector_type(4))) unsigned short u16x4;

#define S_ 4096
#define SD 2048

__device__ __forceinline__ u16 f2bf(float f) {
  union { float f; u32 u; } v; v.f = f;
  u32 r = v.u + 0x7fffu + ((v.u >> 16) & 1u);
  return (u16)(r >> 16);
}
__device__ __forceinline__ float bf2f(u16 x) {
  union { u32 u; float f; } v; v.u = ((u32)x) << 16; return v.f;
}
#if __has_builtin(__builtin_amdgcn_cvt_pk_bf16_f32)
__device__ __forceinline__ u32 pkbf(float a, float b) {
  auto r = __builtin_amdgcn_cvt_pk_bf16_f32(a, b);
  u32 o; __builtin_memcpy(&o, &r, 4); return o;
}
#else
__device__ __forceinline__ u32 pkbf(float a, float b) {
  union { float f; u32 u; } ua, ub; ua.f = a; ub.f = b;
  return __builtin_amdgcn_perm(ub.u + 0x8000u, ua.u + 0x8000u, 0x07060302u);
}
#endif
__device__ __forceinline__ f32x4 mfma16(short8 a, short8 b, f32x4 c) {
  return __builtin_amdgcn_mfma_f32_16x16x32_bf16(a, b, c, 0, 0, 0);
}
__device__ __forceinline__ void async16(const void* g, void* l) {
  __builtin_amdgcn_global_load_lds((__attribute__((address_space(1))) void*)g,
                                   (__attribute__((address_space(3))) void*)l,
                                   16, 0, 0);
}

// attn13 chunk tables: 36 z-slots per (b,h), longest chunks first.
// qt>=8: 3 chunks; qt 4..7: 2 chunks; qt 0..3: 1 chunk.
// dest: 0 -> P0+lpA, 1 -> P1+lpB, 2 -> raw bf16 into Ob + lpC (last chunk), 3 -> direct normalized.
__device__ const signed char ZQT[36] = {15,15,15,14,14,14,13,13,13,12,12,12,11,11,11,10, 7, 7, 3,10,10, 9, 9, 6, 6, 9, 8, 8, 8, 5, 5, 2, 4, 4, 1, 0};
__device__ const signed char ZC0[36] = { 0,11,22, 0,10,20, 0,10,19, 0, 9,18, 0, 8,16, 0, 0, 8, 0, 8,15, 0, 7, 0, 7,14, 0, 6,12, 0, 6, 0, 0, 5, 0, 0};
__device__ const signed char ZC1[36] = {10,21,31, 9,19,29, 9,18,27, 8,17,25, 7,15,23, 7, 7,15, 7,14,21, 6,13, 6,13,19, 5,11,17, 5,11, 5, 4, 9, 3, 1};
__device__ const signed char ZDS[36] = { 0, 1, 2, 0, 1, 2, 0, 1, 2, 0, 1, 2, 0, 1, 2, 0, 0, 2, 3, 1, 2, 0, 1, 0, 2, 2, 0, 1, 2, 0, 2, 3, 0, 2, 3, 3};

// ---------------- fused cast kernel ----------------
__global__ __launch_bounds__(256) void cast_all(const float* __restrict__ hs,
                                                const float* __restrict__ Wq,
                                                const float* __restrict__ Wk,
                                                const float* __restrict__ Wv,
                                                const float* __restrict__ Wo,
                                                u16* __restrict__ dstW,
                                                u16* __restrict__ dstX) {
  int bid = blockIdx.x;
  if (bid < 4096) {
    int gid = bid * 256 + threadIdx.x;
    int wsel = gid >> 18;
    int off  = (gid & 262143) * 4;
    const float* src = (wsel == 0) ? Wq : (wsel == 1) ? Wk : (wsel == 2) ? Wv : Wo;
    float scl = (wsel == 0) ? 0.18033688f : 1.0f;   // 1/sqrt(64)*log2(e) folded into Wq
    f32x4 v = *(const f32x4*)(src + off);
    u16x4 o; o.x = f2bf(v.x * scl); o.y = f2bf(v.y * scl);
    o.z = f2bf(v.z * scl); o.w = f2bf(v.w * scl);
    *(u16x4*)(dstW + (size_t)wsel * 1048576 + off) = o;
  } else {
    int gid = (bid - 4096) * 256 + threadIdx.x;
    int e = gid * 4;
    int m = e >> 10, col = e & 1023;
    int b = m >> 11, sm = m & 2047;
    const float* src = hs + ((size_t)(b * S_ + 2 * sm) << 10) + col;
    f32x4 v = *(const f32x4*)src;
    u16x4 o; o.x = f2bf(v.x); o.y = f2bf(v.y); o.z = f2bf(v.z); o.w = f2bf(v.w);
    *(u16x4*)(dstX + ((size_t)m << 10) + col) = o;
  }
}

// ---------------- 128x128 double-buffered GEMM body (K=1024, B^T), templated epilogue ----------------
// MODE 0: C row-major [.][1024], col n (<1024)                      (Q output)
// MODE 1: K fragment-layout Kp[b][h][kb][key-frag]  (tok=m0+r, d=n-1024, no kappa)
// MODE 2: V fragment-layout Vp[b][h][kb][d-frag]    (m=h*64+d, tok=n, kappa-permuted k)
template<int MODE>
__device__ __forceinline__ void gemm_body128_t(const u16* __restrict__ A,
                                               const u16* __restrict__ B,
                                               u16* __restrict__ C,
                                               int bm, int bn, char* lA, char* lB) {
  const int tid = threadIdx.x, lane = tid & 63, w = tid >> 6;
  const int quad = lane >> 4, l15 = lane & 15;
  const int wm = (w & 1) * 64, wn = (w >> 1) * 64;
  f32x4 acc[4][4] = {};

  auto stage = [&](int buf, int k0) {
#pragma unroll
    for (int i = 0; i < 2; i++) {
      int p = i * 256 + tid;
      int row = p >> 2, cp = p & 3;
      int c = cp ^ ((row ^ (row >> 2)) & 3);
      async16(A + (size_t)(bm + row) * 1024 + k0 + c * 8,
              lA + buf * 8192 + i * 4096 + w * 1024);
      async16(B + (size_t)(bn + row) * 1024 + k0 + c * 8,
              lB + buf * 8192 + i * 4096 + w * 1024);
    }
  };

  stage(0, 0);
#pragma unroll 1
  for (int kt = 0; kt < 32; kt++) {
    __syncthreads();
    if (kt + 1 < 32) stage((kt + 1) & 1, (kt + 1) * 32);
    const char* A_ = lA + (kt & 1) * 8192;
    const char* B_ = lB + (kt & 1) * 8192;
    short8 af[4], bf[4];
#pragma unroll
    for (int mi = 0; mi < 4; mi++) {
      int row = wm + mi * 16 + l15;
      af[mi] = *(const short8*)(A_ + (row * 4 + (quad ^ ((row ^ (row >> 2)) & 3))) * 16);
    }
#pragma unroll
    for (int ni = 0; ni < 4; ni++) {
      int row = wn + ni * 16 + l15;
      bf[ni] = *(const short8*)(B_ + (row * 4 + (quad ^ ((row ^ (row >> 2)) & 3))) * 16);
    }
#pragma unroll
    for (int mi = 0; mi < 4; mi++)
#pragma unroll
      for (int ni = 0; ni < 4; ni++)
        acc[mi][ni] = mfma16(af[mi], bf[ni], acc[mi][ni]);
  }

#pragma unroll
  for (int mi = 0; mi < 4; mi++)
#pragma unroll
    for (int ni = 0; ni < 4; ni++) {
      int m0 = bm + wm + mi * 16 + quad * 4;
      int n = bn + wn + ni * 16 + l15;
      size_t base;
      if (MODE == 0) {
        base = (size_t)m0 * 1024 + n;               // stride 1024 per r
      } else if (MODE == 1) {
        // tok = m0 + r (b, kb, key constant across r since m0 % 4 == 0)
        int bb = m0 >> 11, t = m0 & 2047, kb = t >> 6, key0 = t & 63;
        int d = n - 1024;
        int hh = d >> 6, dd = d & 63, ch = dd >> 3, e = dd & 7;
        base = ((size_t)(((bb * 16 + hh) * 32 + kb)) << 12)
             + (key0 >> 4) * 1024 + (ch >> 2) * 512 + (ch & 3) * 128
             + (key0 & 15) * 8 + e;                  // stride 8 per r
      } else {
        // m = m0 + r = h*64 + d (h, d>>4 constant across r); tok = n
        int hh = m0 >> 6, d0 = m0 & 63;
        int bb = n >> 11, t = n & 2047, kb = t >> 6, kk = t & 63;
        int kh = (kk & 32) | (((kk >> 2) & 3) << 3) | (((kk >> 4) & 1) << 2) | (kk & 3);
        int ch = kh >> 3, e = kh & 7;
        base = ((size_t)(((bb * 16 + hh) * 32 + kb)) << 12)
             + (d0 >> 4) * 1024 + (ch >> 2) * 512 + (ch & 3) * 128
             + (d0 & 15) * 8 + e;                    // stride 8 per r
      }
#pragma unroll
      for (int r = 0; r < 4; r++) {
        size_t off = (MODE == 0) ? base + (size_t)r * 1024 : base + (size_t)r * 8;
        C[off] = f2bf(acc[mi][ni][r]);
      }
    }
}

// fused QKV projection: blocks 0..511 -> Q / Kp from X @ [Wq;Wk]^T (M=4096,N=2048)
//                       blocks 512..767 -> Vp from Wv @ X^T       (M=1024,N=4096)
__global__ __launch_bounds__(256) void qkv_gemm(const u16* __restrict__ X,
                                                const u16* __restrict__ Wbf,
                                                u16* __restrict__ Qb,
                                                u16* __restrict__ Kp,
                                                u16* __restrict__ Vp) {
  __shared__ __align__(16) char lA[16384];
  __shared__ __align__(16) char lB[16384];
  int bid = blockIdx.x;
  if (bid < 512) {
    int bm = (bid >> 4) * 128, bn = (bid & 15) * 128;
    if (bn < 1024) gemm_body128_t<0>(X, Wbf, Qb, bm, bn, lA, lB);
    else           gemm_body128_t<1>(X, Wbf, Kp, bm, bn, lA, lB);
  } else {
    int b2 = bid - 512;
    gemm_body128_t<2>(Wbf + 2 * 1048576, X, Vp, (b2 >> 5) * 128, (b2 & 31) * 128, lA, lB);
  }
}

// ---------------- O-projection: BM=64 x BN=128, wave 32x64 (512 blocks, 24KB) ----------------
__global__ __launch_bounds__(256) void oproj(const u16* __restrict__ A,
                                             const u16* __restrict__ B,
                                             const float* __restrict__ bo,
                                             float* __restrict__ out) {
  __shared__ __align__(16) char lA[8192];    // 2 x 4KB
  __shared__ __align__(16) char lB[16384];   // 2 x 8KB
  const int tid = threadIdx.x, lane = tid & 63, w = tid >> 6;
  const int quad = lane >> 4, l15 = lane & 15;
  const int bm = blockIdx.y * 64, bn = blockIdx.x * 128;
  const int wm = (w & 1) * 32, wn = (w >> 1) * 64;
  f32x4 acc[2][4] = {};

  auto stage = [&](int buf, int k0) {
    {
      int row = tid >> 2, cp = tid & 3;
      int c = cp ^ ((row ^ (row >> 2)) & 3);
      async16(A + (size_t)(bm + row) * 1024 + k0 + c * 8, lA + buf * 4096 + w * 1024);
    }
#pragma unroll
    for (int i = 0; i < 2; i++) {
      int p = i * 256 + tid;
      int row = p >> 2, cp = p & 3;
      int c = cp ^ ((row ^ (row >> 2)) & 3);
      async16(B + (size_t)(bn + row) * 1024 + k0 + c * 8, lB + buf * 8192 + i * 4096 + w * 1024);
    }
  };

  stage(0, 0);
#pragma unroll 1
  for (int kt = 0; kt < 32; kt++) {
    __syncthreads();
    if (kt + 1 < 32) stage((kt + 1) & 1, (kt + 1) * 32);
    const char* A_ = lA + (kt & 1) * 4096;
    const char* B_ = lB + (kt & 1) * 8192;
    short8 af[2], bf[4];
#pragma unroll
    for (int mi = 0; mi < 2; mi++) {
      int row = wm + mi * 16 + l15;
      af[mi] = *(const short8*)(A_ + (row * 4 + (quad ^ ((row ^ (row >> 2)) & 3))) * 16);
    }
#pragma unroll
    for (int ni = 0; ni < 4; ni++) {
      int row = wn + ni * 16 + l15;
      bf[ni] = *(const short8*)(B_ + (row * 4 + (quad ^ ((row ^ (row >> 2)) & 3))) * 16);
    }
#pragma unroll
    for (int mi = 0; mi < 2; mi++)
#pragma unroll
      for (int ni = 0; ni < 4; ni++)
        acc[mi][ni] = mfma16(af[mi], bf[ni], acc[mi][ni]);
  }
#pragma unroll
  for (int mi = 0; mi < 2; mi++)
#pragma unroll
    for (int ni = 0; ni < 4; ni++) {
      int n = bn + wn + ni * 16 + l15;
      float bias = bo[n];
#pragma unroll
      for (int r = 0; r < 4; r++) {
        int m = bm + wm + mi * 16 + quad * 4 + r;   // m = b*2048 + sm
        int bb = m >> 11, sm = m & 2047;
        size_t grow = ((size_t)(bb * S_ + 2 * sm)) << 10;
        out[grow + n] = acc[mi][ni][r] + bias;
        out[grow + 1024 + n] = bias;                // odd row = bo only
      }
    }
}

// ---------------- flash attention v13: attn11 core + 3-way deterministic k-split ----------------
// attn11 proven at 47.5us, grid-limited (12 waves/CU supplied, ~20 permitted). attn12's atomics
// regressed (device-scope atomics bypass L2 -> 210MB HBM writes). v13: 36 z-slots (<=11 tiles),
// grid 1152 = 18 waves/CU supply, STATIC partial destinations (no atomics, no memset):
// chunk0 -> P0(bf16)+lpA, mid chunk -> P1(bf16)+lpB, last chunk -> raw bf16 into Ob + lpC,
// single-chunk rows -> direct normalized write. norm2 combines in place.
__global__ __launch_bounds__(256, 5) void attn13(const u16* __restrict__ Qb,
                                                 const u16* __restrict__ Kp,
                                                 const u16* __restrict__ Vp,
                                                 u16* __restrict__ O,
                                                 u16* __restrict__ P0,
                                                 u16* __restrict__ P1,
                                                 float* __restrict__ lpA,
                                                 float* __restrict__ lpB,
                                                 float* __restrict__ lpC) {
  const int tid = threadIdx.x, lane = tid & 63, w = tid >> 6;
  const int quad = lane >> 4, l15 = lane & 15;
  const int h = blockIdx.x, b = blockIdx.y;
  const int z = (int)blockIdx.z;
  const int qt = ZQT[z], c0 = ZC0[z], c1 = ZC1[z], dest = ZDS[z];
  const int qb = qt * 128 + w * 32;
  const int qt2 = 2 * qt;            // first diagonal k-tile

  short8 qf[2][2];
#pragma unroll
  for (int n = 0; n < 2; n++) {
    const u16* qp = Qb + (size_t)(b * SD + qb + n * 16 + l15) * 1024 + h * 64 + quad * 8;
    qf[n][0] = *(const short8*)qp;
    qf[n][1] = *(const short8*)(qp + 32);
  }

  const size_t bh = (size_t)(b * 16 + h) * 32;
  f32x4 oacc[2][4] = {};
  f32x4 l4v[2] = {};
  const f32x4 zf = {};

#pragma unroll 1
  for (int kt = c0; kt <= c1; kt++) {
    const u16* K_ = Kp + ((bh + kt) << 12);
    const u16* V_ = Vp + ((bh + kt) << 12);
    const bool diag = (kt >= qt2);   // wave-uniform

    short8 kf[4][2];
#pragma unroll
    for (int m = 0; m < 4; m++) {
      kf[m][0] = *(const short8*)(K_ + m * 1024 + lane * 8);
      kf[m][1] = *(const short8*)(K_ + m * 1024 + 512 + lane * 8);
    }
    f32x4 s[4][2];
#pragma unroll
    for (int m = 0; m < 4; m++)
#pragma unroll
      for (int n = 0; n < 2; n++) {
        f32x4 a = mfma16(kf[m][0], qf[n][0], zf);
        s[m][n] = mfma16(kf[m][1], qf[n][1], a);
      }
    short8 vf[4][2];
#pragma unroll
    for (int m = 0; m < 4; m++) {
      vf[m][0] = *(const short8*)(V_ + m * 1024 + lane * 8);
      vf[m][1] = *(const short8*)(V_ + m * 1024 + 512 + lane * 8);
    }
    u32 pw[2][8];
#pragma unroll
    for (int m = 0; m < 4; m++)
#pragma unroll
      for (int n = 0; n < 2; n++) {
        f32x4 a = s[m][n];
        if (diag) {
          int qrel = w * 32 + n * 16 + l15;
          int kd = (kt - qt2) * 64 + m * 16 + quad * 4;
#pragma unroll
          for (int r = 0; r < 4; r++)
            if (kd + r > qrel) a[r] = -1e30f;
        }
        f32x4 p;
#pragma unroll
        for (int r = 0; r < 4; r++) p[r] = exp2f(a[r]);
        l4v[n] += p;
        pw[n][m * 2]     = pkbf(p[0], p[1]);
        pw[n][m * 2 + 1] = pkbf(p[2], p[3]);
      }
    short8 pf[2][2];
#pragma unroll
    for (int n = 0; n < 2; n++) {
      __builtin_memcpy(&pf[n][0], &pw[n][0], 16);
      __builtin_memcpy(&pf[n][1], &pw[n][4], 16);
    }
#pragma unroll
    for (int m = 0; m < 4; m++)
#pragma unroll
      for (int n = 0; n < 2; n++) {
        oacc[n][m] = mfma16(vf[m][0], pf[n][0], oacc[n][m]);
        oacc[n][m] = mfma16(vf[m][1], pf[n][1], oacc[n][m]);
      }
  }

#pragma unroll
  for (int n = 0; n < 2; n++) {
    float l = (l4v[n][0] + l4v[n][1]) + (l4v[n][2] + l4v[n][3]);
    l += __shfl_xor(l, 16, 64);
    l += __shfl_xor(l, 32, 64);
    const int q = qb + n * 16 + l15;             // row within [0, 2048)
    if (dest == 3) {
      float inv = 1.0f / l;
      u16* op = O + (size_t)(b * SD + q) * 1024 + h * 64;
#pragma unroll
      for (int m = 0; m < 4; m++) {
        u16x4 ov;
#pragma unroll
        for (int r = 0; r < 4; r++) ov[r] = f2bf(oacc[n][m][r] * inv);
        *(u16x4*)(op + m * 16 + quad * 4) = ov;
      }
    } else {
      u16* pdst;
      if (dest == 0) {
        int rq = b * 1536 + (q - 512);           // qt>=4 -> q>=512
        pdst = P0 + ((size_t)rq << 10) + h * 64 + quad * 4;
        if (quad == 0) lpA[rq * 16 + h] = l;
      } else if (dest == 1) {
        int rq = b * 1024 + (q - 1024);          // qt>=8 -> q>=1024
        pdst = P1 + ((size_t)rq << 10) + h * 64 + quad * 4;
        if (quad == 0) lpB[rq * 16 + h] = l;
      } else {
        pdst = O + (size_t)(b * SD + q) * 1024 + h * 64 + quad * 4;
        int rq = b * 1536 + (q - 512);
        if (quad == 0) lpC[rq * 16 + h] = l;
      }
#pragma unroll
      for (int m = 0; m < 4; m++) {
        u16x4 ov;
#pragma unroll
        for (int r = 0; r < 4; r++) ov[r] = f2bf(oacc[n][m][r]);
        *(u16x4*)(pdst + m * 16) = ov;
      }
    }
  }
}

// ---------------- combine partials in place for rows q in [512,2048): O = (P0 + P1? + O_raw)/l ----
__global__ __launch_bounds__(256) void norm2(const u16* __restrict__ P0,
                                             const u16* __restrict__ P1,
                                             const float* __restrict__ lpA,
                                             const float* __restrict__ lpB,
                                             const float* __restrict__ lpC,
                                             u16* __restrict__ O) {
  int gid = blockIdx.x * 256 + threadIdx.x;    // 3072 blocks -> 3072 rows x 256 col-groups
  int row = gid >> 8;                          // [0, 3072) = b*1536 + (q-512)
  int d0 = (gid & 255) * 4;
  int hh = d0 >> 6;
  int b = row >= 1536 ? 1 : 0;
  int qr = row - b * 1536;                     // q = 512 + qr
  float l = lpA[row * 16 + hh] + lpC[row * 16 + hh];
  u16x4 a0 = *(const u16x4*)(P0 + ((size_t)row << 10) + d0);
  u16* op = O + ((size_t)(b * SD + 512 + qr) << 10) + d0;
  u16x4 ar = *(const u16x4*)op;
  f32x4 acc;
#pragma unroll
  for (int r = 0; r < 4; r++) acc[r] = bf2f(a0[r]) + bf2f(ar[r]);
  if (qr >= 512) {                             // 3-way rows (qt>=8)
    int r1 = b * 1024 + (qr - 512);
    l += lpB[r1 * 16 + hh];
    u16x4 a1 = *(const u16x4*)(P1 + ((size_t)r1 << 10) + d0);
#pragma unroll
    for (int r = 0; r < 4; r++) acc[r] += bf2f(a1[r]);
  }
  float inv = 1.0f / l;
  u16x4 o;
#pragma unroll
  for (int r = 0; r < 4; r++) o[r] = f2bf(acc[r] * inv);
  *(u16x4*)op = o;
}

// ---------------- host ----------------
extern "C" void kernel_launch(void* const* d_in, const int* in_sizes, int n_in,
                              void* d_out, int out_size, void* d_ws, size_t ws_size,
                              hipStream_t stream) {
  (void)in_sizes; (void)n_in; (void)out_size; (void)ws_size;
  const float* hs = (const float*)d_in[0];
  const float* Wq = (const float*)d_in[1];
  const float* Wk = (const float*)d_in[2];
  const float* Wv = (const float*)d_in[3];
  const float* Wo = (const float*)d_in[4];
  const float* bo = (const float*)d_in[5];
  float* out = (float*)d_out;
  char* ws = (char*)d_ws;

  u16* Xbf = (u16*)ws;                            // [4096][1024] even-row hs, bf16 (dead after qkv_gemm)
  u16* Wbf = (u16*)(ws + (8u << 20));             // 4 x [1024][1024] bf16; q,k,v dead after qkv_gemm, Wo (14-16MB) live
  u16* Qb  = (u16*)(ws + (16u << 20));            // [4096][1024]  Q (pre-scaled, log2 domain)
  u16* Kp  = (u16*)(ws + (24u << 20));            // [2][16][32][4096] K fragment-order
  u16* Vp  = (u16*)(ws + (32u << 20));            // [2][16][32][4096] V fragment-order (kappa)
  u16* Ob  = (u16*)(ws + (40u << 20));            // [4096][1024]  attn out

  u16*   P0  = (u16*)ws;                          // bf16 partials [3072][1024] = 6MB (dead Xbf)
  u16*   P1  = (u16*)(ws + (6u << 20));           // bf16 partials [2048][1024] = 4MB (dead Xbf/Wq)
  float* lpA = (float*)(ws + (10u << 20));                   // [3072][16] f32 = 192KB (dead Wk)
  float* lpB = (float*)(ws + (10u << 20) + (256u << 10));    // [2048][16] f32 = 128KB
  float* lpC = (float*)(ws + (10u << 20) + (512u << 10));    // [3072][16] f32 = 192KB

  cast_all<<<8192, 256, 0, stream>>>(hs, Wq, Wk, Wv, Wo, Wbf, Xbf);
  qkv_gemm<<<768, 256, 0, stream>>>(Xbf, Wbf, Qb, Kp, Vp);
  attn13<<<dim3(16, 2, 36), 256, 0, stream>>>(Qb, Kp, Vp, Ob, P0, P1, lpA, lpB, lpC);
  norm2<<<3072, 256, 0, stream>>>(P0, P1, lpA, lpB, lpC, Ob);
  oproj<<<dim3(8, 64), 256, 0, stream>>>(Ob, Wbf + 3 * 1048576, bo, out);
}

// Round 11
// 198.676 us; speedup vs baseline: 1.6759x; 1.5017x over previous
//
#include <hip/hip_runtime.h>
#include <cstdint>

typedef unsigned short u16;
typedef unsigned int u32;
typedef __attribute__((ext_vector_type(8))) short short8;   // 8 x bf16 bits
typedef __attribute__((ext_vector_type(4))) float f32x4;
typedef __attribute__((ext_vector_type(4))) unsigned short u16x4;

#define S_ 4096
#define SD 2048

__device__ __forceinline__ u16 f2bf(float f) {
  union { float f; u32 u; } v; v.f = f;
  u32 r = v.u + 0x7fffu + ((v.u >> 16) & 1u);
  return (u16)(r >> 16);
}
__device__ __forceinline__ float bf2f(u16 x) {
  union { u32 u; float f; } v; v.u = ((u32)x) << 16; return v.f;
}
#if __has_builtin(__builtin_amdgcn_cvt_pk_bf16_f32)
__device__ __forceinline__ u32 pkbf(float a, float b) {
  auto r = __builtin_amdgcn_cvt_pk_bf16_f32(a, b);
  u32 o; __builtin_memcpy(&o, &r, 4); return o;
}
#else
__device__ __forceinline__ u32 pkbf(float a, float b) {
  union { float f; u32 u; } ua, ub; ua.f = a; ub.f = b;
  return __builtin_amdgcn_perm(ub.u + 0x8000u, ua.u + 0x8000u, 0x07060302u);
}
#endif
__device__ __forceinline__ f32x4 mfma16(short8 a, short8 b, f32x4 c) {
  return __builtin_amdgcn_mfma_f32_16x16x32_bf16(a, b, c, 0, 0, 0);
}
__device__ __forceinline__ void async16(const void* g, void* l) {
  __builtin_amdgcn_global_load_lds((__attribute__((address_space(1))) void*)g,
                                   (__attribute__((address_space(3))) void*)l,
                                   16, 0, 0);
}

// attn13 chunk tables: 36 z-slots per (b,h), longest chunks first.
// qt>=8: 3 chunks; qt 4..7: 2 chunks; qt 0..3: 1 chunk.
// dest: 0 -> P0+lpA, 1 -> P1+lpB, 2 -> raw bf16 into Ob + lpC (last chunk), 3 -> direct normalized.
__device__ const signed char ZQT[36] = {15,15,15,14,14,14,13,13,13,12,12,12,11,11,11,10, 7, 7, 3,10,10, 9, 9, 6, 6, 9, 8, 8, 8, 5, 5, 2, 4, 4, 1, 0};
__device__ const signed char ZC0[36] = { 0,11,22, 0,10,20, 0,10,19, 0, 9,18, 0, 8,16, 0, 0, 8, 0, 8,15, 0, 7, 0, 7,14, 0, 6,12, 0, 6, 0, 0, 5, 0, 0};
__device__ const signed char ZC1[36] = {10,21,31, 9,19,29, 9,18,27, 8,17,25, 7,15,23, 7, 7,15, 7,14,21, 6,13, 6,13,19, 5,11,17, 5,11, 5, 4, 9, 3, 1};
__device__ const signed char ZDS[36] = { 0, 1, 2, 0, 1, 2, 0, 1, 2, 0, 1, 2, 0, 1, 2, 0, 0, 2, 3, 1, 2, 0, 1, 0, 2, 2, 0, 1, 2, 0, 2, 3, 0, 2, 3, 3};

// ---------------- fused cast kernel ----------------
__global__ __launch_bounds__(256) void cast_all(const float* __restrict__ hs,
                                                const float* __restrict__ Wq,
                                                const float* __restrict__ Wk,
                                                const float* __restrict__ Wv,
                                                const float* __restrict__ Wo,
                                                u16* __restrict__ dstW,
                                                u16* __restrict__ dstX) {
  int bid = blockIdx.x;
  if (bid < 4096) {
    int gid = bid * 256 + threadIdx.x;
    int wsel = gid >> 18;
    int off  = (gid & 262143) * 4;
    const float* src = (wsel == 0) ? Wq : (wsel == 1) ? Wk : (wsel == 2) ? Wv : Wo;
    float scl = (wsel == 0) ? 0.18033688f : 1.0f;   // 1/sqrt(64)*log2(e) folded into Wq
    f32x4 v = *(const f32x4*)(src + off);
    u16x4 o; o.x = f2bf(v.x * scl); o.y = f2bf(v.y * scl);
    o.z = f2bf(v.z * scl); o.w = f2bf(v.w * scl);
    *(u16x4*)(dstW + (size_t)wsel * 1048576 + off) = o;
  } else {
    int gid = (bid - 4096) * 256 + threadIdx.x;
    int e = gid * 4;
    int m = e >> 10, col = e & 1023;
    int b = m >> 11, sm = m & 2047;
    const float* src = hs + ((size_t)(b * S_ + 2 * sm) << 10) + col;
    f32x4 v = *(const f32x4*)src;
    u16x4 o; o.x = f2bf(v.x); o.y = f2bf(v.y); o.z = f2bf(v.z); o.w = f2bf(v.w);
    *(u16x4*)(dstX + ((size_t)m << 10) + col) = o;
  }
}

// ---------------- 128x128 double-buffered GEMM body (K=1024, B^T), templated epilogue ----------------
// MODE 0: C row-major [.][1024], col n (<1024)                      (Q output)
// MODE 1: K fragment-layout Kp[b][h][kb][key-frag]  (tok=m0+r, d=n-1024, no kappa)
// MODE 2: V fragment-layout Vp[b][h][kb][d-frag]    (m=h*64+d, tok=n, kappa-permuted k)
template<int MODE>
__device__ __forceinline__ void gemm_body128_t(const u16* __restrict__ A,
                                               const u16* __restrict__ B,
                                               u16* __restrict__ C,
                                               int bm, int bn, char* lA, char* lB) {
  const int tid = threadIdx.x, lane = tid & 63, w = tid >> 6;
  const int quad = lane >> 4, l15 = lane & 15;
  const int wm = (w & 1) * 64, wn = (w >> 1) * 64;
  f32x4 acc[4][4] = {};

  auto stage = [&](int buf, int k0) {
#pragma unroll
    for (int i = 0; i < 2; i++) {
      int p = i * 256 + tid;
      int row = p >> 2, cp = p & 3;
      int c = cp ^ ((row ^ (row >> 2)) & 3);
      async16(A + (size_t)(bm + row) * 1024 + k0 + c * 8,
              lA + buf * 8192 + i * 4096 + w * 1024);
      async16(B + (size_t)(bn + row) * 1024 + k0 + c * 8,
              lB + buf * 8192 + i * 4096 + w * 1024);
    }
  };

  stage(0, 0);
#pragma unroll 1
  for (int kt = 0; kt < 32; kt++) {
    __syncthreads();
    if (kt + 1 < 32) stage((kt + 1) & 1, (kt + 1) * 32);
    const char* A_ = lA + (kt & 1) * 8192;
    const char* B_ = lB + (kt & 1) * 8192;
    short8 af[4], bf[4];
#pragma unroll
    for (int mi = 0; mi < 4; mi++) {
      int row = wm + mi * 16 + l15;
      af[mi] = *(const short8*)(A_ + (row * 4 + (quad ^ ((row ^ (row >> 2)) & 3))) * 16);
    }
#pragma unroll
    for (int ni = 0; ni < 4; ni++) {
      int row = wn + ni * 16 + l15;
      bf[ni] = *(const short8*)(B_ + (row * 4 + (quad ^ ((row ^ (row >> 2)) & 3))) * 16);
    }
#pragma unroll
    for (int mi = 0; mi < 4; mi++)
#pragma unroll
      for (int ni = 0; ni < 4; ni++)
        acc[mi][ni] = mfma16(af[mi], bf[ni], acc[mi][ni]);
  }

#pragma unroll
  for (int mi = 0; mi < 4; mi++)
#pragma unroll
    for (int ni = 0; ni < 4; ni++) {
      int m0 = bm + wm + mi * 16 + quad * 4;
      int n = bn + wn + ni * 16 + l15;
      size_t base;
      if (MODE == 0) {
        base = (size_t)m0 * 1024 + n;               // stride 1024 per r
      } else if (MODE == 1) {
        // tok = m0 + r (b, kb, key constant across r since m0 % 4 == 0)
        int bb = m0 >> 11, t = m0 & 2047, kb = t >> 6, key0 = t & 63;
        int d = n - 1024;
        int hh = d >> 6, dd = d & 63, ch = dd >> 3, e = dd & 7;
        base = ((size_t)(((bb * 16 + hh) * 32 + kb)) << 12)
             + (key0 >> 4) * 1024 + (ch >> 2) * 512 + (ch & 3) * 128
             + (key0 & 15) * 8 + e;                  // stride 8 per r
      } else {
        // m = m0 + r = h*64 + d (h, d>>4 constant across r); tok = n
        int hh = m0 >> 6, d0 = m0 & 63;
        int bb = n >> 11, t = n & 2047, kb = t >> 6, kk = t & 63;
        int kh = (kk & 32) | (((kk >> 2) & 3) << 3) | (((kk >> 4) & 1) << 2) | (kk & 3);
        int ch = kh >> 3, e = kh & 7;
        base = ((size_t)(((bb * 16 + hh) * 32 + kb)) << 12)
             + (d0 >> 4) * 1024 + (ch >> 2) * 512 + (ch & 3) * 128
             + (d0 & 15) * 8 + e;                    // stride 8 per r
      }
#pragma unroll
      for (int r = 0; r < 4; r++) {
        size_t off = (MODE == 0) ? base + (size_t)r * 1024 : base + (size_t)r * 8;
        C[off] = f2bf(acc[mi][ni][r]);
      }
    }
}

// fused QKV projection: blocks 0..511 -> Q / Kp from X @ [Wq;Wk]^T (M=4096,N=2048)
//                       blocks 512..767 -> Vp from Wv @ X^T       (M=1024,N=4096)
__global__ __launch_bounds__(256) void qkv_gemm(const u16* __restrict__ X,
                                                const u16* __restrict__ Wbf,
                                                u16* __restrict__ Qb,
                                                u16* __restrict__ Kp,
                                                u16* __restrict__ Vp) {
  __shared__ __align__(16) char lA[16384];
  __shared__ __align__(16) char lB[16384];
  int bid = blockIdx.x;
  if (bid < 512) {
    int bm = (bid >> 4) * 128, bn = (bid & 15) * 128;
    if (bn < 1024) gemm_body128_t<0>(X, Wbf, Qb, bm, bn, lA, lB);
    else           gemm_body128_t<1>(X, Wbf, Kp, bm, bn, lA, lB);
  } else {
    int b2 = bid - 512;
    gemm_body128_t<2>(Wbf + 2 * 1048576, X, Vp, (b2 >> 5) * 128, (b2 & 31) * 128, lA, lB);
  }
}

// ---------------- O-projection: BM=64 x BN=128, wave 32x64 (512 blocks, 24KB) ----------------
__global__ __launch_bounds__(256) void oproj(const u16* __restrict__ A,
                                             const u16* __restrict__ B,
                                             const float* __restrict__ bo,
                                             float* __restrict__ out) {
  __shared__ __align__(16) char lA[8192];    // 2 x 4KB
  __shared__ __align__(16) char lB[16384];   // 2 x 8KB
  const int tid = threadIdx.x, lane = tid & 63, w = tid >> 6;
  const int quad = lane >> 4, l15 = lane & 15;
  const int bm = blockIdx.y * 64, bn = blockIdx.x * 128;
  const int wm = (w & 1) * 32, wn = (w >> 1) * 64;
  f32x4 acc[2][4] = {};

  auto stage = [&](int buf, int k0) {
    {
      int row = tid >> 2, cp = tid & 3;
      int c = cp ^ ((row ^ (row >> 2)) & 3);
      async16(A + (size_t)(bm + row) * 1024 + k0 + c * 8, lA + buf * 4096 + w * 1024);
    }
#pragma unroll
    for (int i = 0; i < 2; i++) {
      int p = i * 256 + tid;
      int row = p >> 2, cp = p & 3;
      int c = cp ^ ((row ^ (row >> 2)) & 3);
      async16(B + (size_t)(bn + row) * 1024 + k0 + c * 8, lB + buf * 8192 + i * 4096 + w * 1024);
    }
  };

  stage(0, 0);
#pragma unroll 1
  for (int kt = 0; kt < 32; kt++) {
    __syncthreads();
    if (kt + 1 < 32) stage((kt + 1) & 1, (kt + 1) * 32);
    const char* A_ = lA + (kt & 1) * 4096;
    const char* B_ = lB + (kt & 1) * 8192;
    short8 af[2], bf[4];
#pragma unroll
    for (int mi = 0; mi < 2; mi++) {
      int row = wm + mi * 16 + l15;
      af[mi] = *(const short8*)(A_ + (row * 4 + (quad ^ ((row ^ (row >> 2)) & 3))) * 16);
    }
#pragma unroll
    for (int ni = 0; ni < 4; ni++) {
      int row = wn + ni * 16 + l15;
      bf[ni] = *(const short8*)(B_ + (row * 4 + (quad ^ ((row ^ (row >> 2)) & 3))) * 16);
    }
#pragma unroll
    for (int mi = 0; mi < 2; mi++)
#pragma unroll
      for (int ni = 0; ni < 4; ni++)
        acc[mi][ni] = mfma16(af[mi], bf[ni], acc[mi][ni]);
  }
#pragma unroll
  for (int mi = 0; mi < 2; mi++)
#pragma unroll
    for (int ni = 0; ni < 4; ni++) {
      int n = bn + wn + ni * 16 + l15;
      float bias = bo[n];
#pragma unroll
      for (int r = 0; r < 4; r++) {
        int m = bm + wm + mi * 16 + quad * 4 + r;   // m = b*2048 + sm
        int bb = m >> 11, sm = m & 2047;
        size_t grow = ((size_t)(bb * S_ + 2 * sm)) << 10;
        out[grow + n] = acc[mi][ni][r] + bias;
        out[grow + 1024 + n] = bias;                // odd row = bo only
      }
    }
}

// ---------------- flash attention v13b: attn13 with the spill bug fixed ----------------
// Round-10 root cause: __launch_bounds__(256,5) forced VGPR cap ~102 -> allocator at 48 ->
// oacc spilled to scratch -> 585MB scratch traffic, 141us. (256,3) = attn11-proven setting
// (VGPR=80, zero scratch). Everything else unchanged: 36 z-slots (<=11 tiles), grid 1152 =
// 18 waves/CU supply (HW permits 24 at VGPR=80), static partials, no atomics, no memset.
__global__ __launch_bounds__(256, 3) void attn13(const u16* __restrict__ Qb,
                                                 const u16* __restrict__ Kp,
                                                 const u16* __restrict__ Vp,
                                                 u16* __restrict__ O,
                                                 u16* __restrict__ P0,
                                                 u16* __restrict__ P1,
                                                 float* __restrict__ lpA,
                                                 float* __restrict__ lpB,
                                                 float* __restrict__ lpC) {
  const int tid = threadIdx.x, lane = tid & 63, w = tid >> 6;
  const int quad = lane >> 4, l15 = lane & 15;
  const int h = blockIdx.x, b = blockIdx.y;
  const int z = (int)blockIdx.z;
  const int qt = ZQT[z], c0 = ZC0[z], c1 = ZC1[z], dest = ZDS[z];
  const int qb = qt * 128 + w * 32;
  const int qt2 = 2 * qt;            // first diagonal k-tile

  short8 qf[2][2];
#pragma unroll
  for (int n = 0; n < 2; n++) {
    const u16* qp = Qb + (size_t)(b * SD + qb + n * 16 + l15) * 1024 + h * 64 + quad * 8;
    qf[n][0] = *(const short8*)qp;
    qf[n][1] = *(const short8*)(qp + 32);
  }

  const size_t bh = (size_t)(b * 16 + h) * 32;
  f32x4 oacc[2][4] = {};
  f32x4 l4v[2] = {};
  const f32x4 zf = {};

#pragma unroll 1
  for (int kt = c0; kt <= c1; kt++) {
    const u16* K_ = Kp + ((bh + kt) << 12);
    const u16* V_ = Vp + ((bh + kt) << 12);
    const bool diag = (kt >= qt2);   // wave-uniform

    short8 kf[4][2];
#pragma unroll
    for (int m = 0; m < 4; m++) {
      kf[m][0] = *(const short8*)(K_ + m * 1024 + lane * 8);
      kf[m][1] = *(const short8*)(K_ + m * 1024 + 512 + lane * 8);
    }
    f32x4 s[4][2];
#pragma unroll
    for (int m = 0; m < 4; m++)
#pragma unroll
      for (int n = 0; n < 2; n++) {
        f32x4 a = mfma16(kf[m][0], qf[n][0], zf);
        s[m][n] = mfma16(kf[m][1], qf[n][1], a);
      }
    short8 vf[4][2];
#pragma unroll
    for (int m = 0; m < 4; m++) {
      vf[m][0] = *(const short8*)(V_ + m * 1024 + lane * 8);
      vf[m][1] = *(const short8*)(V_ + m * 1024 + 512 + lane * 8);
    }
    u32 pw[2][8];
#pragma unroll
    for (int m = 0; m < 4; m++)
#pragma unroll
      for (int n = 0; n < 2; n++) {
        f32x4 a = s[m][n];
        if (diag) {
          int qrel = w * 32 + n * 16 + l15;
          int kd = (kt - qt2) * 64 + m * 16 + quad * 4;
#pragma unroll
          for (int r = 0; r < 4; r++)
            if (kd + r > qrel) a[r] = -1e30f;
        }
        f32x4 p;
#pragma unroll
        for (int r = 0; r < 4; r++) p[r] = exp2f(a[r]);
        l4v[n] += p;
        pw[n][m * 2]     = pkbf(p[0], p[1]);
        pw[n][m * 2 + 1] = pkbf(p[2], p[3]);
      }
    short8 pf[2][2];
#pragma unroll
    for (int n = 0; n < 2; n++) {
      __builtin_memcpy(&pf[n][0], &pw[n][0], 16);
      __builtin_memcpy(&pf[n][1], &pw[n][4], 16);
    }
#pragma unroll
    for (int m = 0; m < 4; m++)
#pragma unroll
      for (int n = 0; n < 2; n++) {
        oacc[n][m] = mfma16(vf[m][0], pf[n][0], oacc[n][m]);
        oacc[n][m] = mfma16(vf[m][1], pf[n][1], oacc[n][m]);
      }
  }

#pragma unroll
  for (int n = 0; n < 2; n++) {
    float l = (l4v[n][0] + l4v[n][1]) + (l4v[n][2] + l4v[n][3]);
    l += __shfl_xor(l, 16, 64);
    l += __shfl_xor(l, 32, 64);
    const int q = qb + n * 16 + l15;             // row within [0, 2048)
    if (dest == 3) {
      float inv = 1.0f / l;
      u16* op = O + (size_t)(b * SD + q) * 1024 + h * 64;
#pragma unroll
      for (int m = 0; m < 4; m++) {
        u16x4 ov;
#pragma unroll
        for (int r = 0; r < 4; r++) ov[r] = f2bf(oacc[n][m][r] * inv);
        *(u16x4*)(op + m * 16 + quad * 4) = ov;
      }
    } else {
      u16* pdst;
      if (dest == 0) {
        int rq = b * 1536 + (q - 512);           // qt>=4 -> q>=512
        pdst = P0 + ((size_t)rq << 10) + h * 64 + quad * 4;
        if (quad == 0) lpA[rq * 16 + h] = l;
      } else if (dest == 1) {
        int rq = b * 1024 + (q - 1024);          // qt>=8 -> q>=1024
        pdst = P1 + ((size_t)rq << 10) + h * 64 + quad * 4;
        if (quad == 0) lpB[rq * 16 + h] = l;
      } else {
        pdst = O + (size_t)(b * SD + q) * 1024 + h * 64 + quad * 4;
        int rq = b * 1536 + (q - 512);
        if (quad == 0) lpC[rq * 16 + h] = l;
      }
#pragma unroll
      for (int m = 0; m < 4; m++) {
        u16x4 ov;
#pragma unroll
        for (int r = 0; r < 4; r++) ov[r] = f2bf(oacc[n][m][r]);
        *(u16x4*)(pdst + m * 16) = ov;
      }
    }
  }
}

// ---------------- combine partials in place for rows q in [512,2048): O = (P0 + P1? + O_raw)/l ----
__global__ __launch_bounds__(256) void norm2(const u16* __restrict__ P0,
                                             const u16* __restrict__ P1,
                                             const float* __restrict__ lpA,
                                             const float* __restrict__ lpB,
                                             const float* __restrict__ lpC,
                                             u16* __restrict__ O) {
  int gid = blockIdx.x * 256 + threadIdx.x;    // 3072 blocks -> 3072 rows x 256 col-groups
  int row = gid >> 8;                          // [0, 3072) = b*1536 + (q-512)
  int d0 = (gid & 255) * 4;
  int hh = d0 >> 6;
  int b = row >= 1536 ? 1 : 0;
  int qr = row - b * 1536;                     // q = 512 + qr
  float l = lpA[row * 16 + hh] + lpC[row * 16 + hh];
  u16x4 a0 = *(const u16x4*)(P0 + ((size_t)row << 10) + d0);
  u16* op = O + ((size_t)(b * SD + 512 + qr) << 10) + d0;
  u16x4 ar = *(const u16x4*)op;
  f32x4 acc;
#pragma unroll
  for (int r = 0; r < 4; r++) acc[r] = bf2f(a0[r]) + bf2f(ar[r]);
  if (qr >= 512) {                             // 3-way rows (qt>=8)
    int r1 = b * 1024 + (qr - 512);
    l += lpB[r1 * 16 + hh];
    u16x4 a1 = *(const u16x4*)(P1 + ((size_t)r1 << 10) + d0);
#pragma unroll
    for (int r = 0; r < 4; r++) acc[r] += bf2f(a1[r]);
  }
  float inv = 1.0f / l;
  u16x4 o;
#pragma unroll
  for (int r = 0; r < 4; r++) o[r] = f2bf(acc[r] * inv);
  *(u16x4*)op = o;
}

// ---------------- host ----------------
extern "C" void kernel_launch(void* const* d_in, const int* in_sizes, int n_in,
                              void* d_out, int out_size, void* d_ws, size_t ws_size,
                              hipStream_t stream) {
  (void)in_sizes; (void)n_in; (void)out_size; (void)ws_size;
  const float* hs = (const float*)d_in[0];
  const float* Wq = (const float*)d_in[1];
  const float* Wk = (const float*)d_in[2];
  const float* Wv = (const float*)d_in[3];
  const float* Wo = (const float*)d_in[4];
  const float* bo = (const float*)d_in[5];
  float* out = (float*)d_out;
  char* ws = (char*)d_ws;

  u16* Xbf = (u16*)ws;                            // [4096][1024] even-row hs, bf16 (dead after qkv_gemm)
  u16* Wbf = (u16*)(ws + (8u << 20));             // 4 x [1024][1024] bf16; q,k,v dead after qkv_gemm, Wo (14-16MB) live
  u16* Qb  = (u16*)(ws + (16u << 20));            // [4096][1024]  Q (pre-scaled, log2 domain)
  u16* Kp  = (u16*)(ws + (24u << 20));            // [2][16][32][4096] K fragment-order
  u16* Vp  = (u16*)(ws + (32u << 20));            // [2][16][32][4096] V fragment-order (kappa)
  u16* Ob  = (u16*)(ws + (40u << 20));            // [4096][1024]  attn out

  u16*   P0  = (u16*)ws;                          // bf16 partials [3072][1024] = 6MB (dead Xbf)
  u16*   P1  = (u16*)(ws + (6u << 20));           // bf16 partials [2048][1024] = 4MB (dead Xbf/Wq)
  float* lpA = (float*)(ws + (10u << 20));                   // [3072][16] f32 = 192KB (dead Wk)
  float* lpB = (float*)(ws + (10u << 20) + (256u << 10));    // [2048][16] f32 = 128KB
  float* lpC = (float*)(ws + (10u << 20) + (512u << 10));    // [3072][16] f32 = 192KB

  cast_all<<<8192, 256, 0, stream>>>(hs, Wq, Wk, Wv, Wo, Wbf, Xbf);
  qkv_gemm<<<768, 256, 0, stream>>>(Xbf, Wbf, Qb, Kp, Vp);
  attn13<<<dim3(16, 2, 36), 256, 0, stream>>>(Qb, Kp, Vp, Ob, P0, P1, lpA, lpB, lpC);
  norm2<<<3072, 256, 0, stream>>>(P0, P1, lpA, lpB, lpC, Ob);
  oproj<<<dim3(8, 64), 256, 0, stream>>>(Ob, Wbf + 3 * 1048576, bo, out);
}